// Round 12
// baseline (844.215 us; speedup 1.0000x reference)
//
#include <hip/hip_runtime.h>
#include <cmath>

// Problem constants (from reference)
#define NN  5      // N_NODES
#define BB  4      // batch
#define CCH 256    // channels
#define HWD 1024   // H*W
#define THRESH_V 0.3f
#define EPS_V 1e-12f

// R12: DMA staging via __builtin_amdgcn_global_load_lds (16B/lane, zero
// staging VGPRs, zero ds_write VALU cost) + column-swizzled LDS layout
// (conflict-free ds_read_b128) + ONE barrier per K-chunk double-buffer.
// Swizzle: 16-float4 "cells" per 64-float row; cell c stored at position
// pos(c) = ((c&1)<<3)|(c>>1); applied to per-lane GLOBAL source addresses
// (LDS dest stays linear, as DMA requires); reads use pos(2g)=g (x0/a0) and
// pos(2g+1)=8+g (x1/a1) -> 8 lane-groups hit 8 distinct bank-quads.
// Per chunk: waves 0-4 DMA their own X panel (2 calls), wave 5 DMAs A+W2 (4).

#define CT 64      // channel rows per block
#define WT 64      // hw cols per block
#define KC 8       // k chunk
#define SPAD 68    // Es row stride (floats) in epilogue

#define W2T_OFF (NN * CCH * CCH)      // second table in ws

// buffer layout (floats): Xs[5][8][64] @0 | As[8][64] @2560 | W2s[8][64] @3072
#define BUFSZ 3584
#define ASO   2560
#define W2SO  3072
#define SMEM_FLOATS (2 * BUFSZ)       // 7168 floats = 28672 B
// epilogue overlay Es[6][16][68] = 6528 floats (fits)

// DMA: 16B per lane; LDS dest must be wave-uniform (data lands at dest+lane*16)
#define GL16(GSRC, LDST)                                                    \
    __builtin_amdgcn_global_load_lds(                                       \
        (const __attribute__((address_space(1))) unsigned int*)(GSRC),      \
        (__attribute__((address_space(3))) unsigned int*)(LDST), 16, 0, 0)

// ---------------- prep: coalesced LDS-tile transpose of conv_w ----------------
// ws: At[i][k][c] = W1[i][c][k] + W2[i][c][k];  W2t[i][k][c] = W2[i][c][k]
__global__ void fub_prep(const float* __restrict__ conv_w, float* __restrict__ ws)
{
    __shared__ float Ta[64 * 68];
    __shared__ float Tw[64 * 68];
    const int u  = threadIdx.x;
    int bid = blockIdx.x;
    const int cb = bid & 3;  bid >>= 2;
    const int kb = bid & 3;  bid >>= 2;
    const int i  = bid;                   // 0..4

    // phase 1: coalesced read along k; store [c_local][k_local] (pad 68)
#pragma unroll
    for (int p = 0; p < 4; ++p) {
        const int cl = p * 16 + (u >> 4);
        const int kq = (u & 15) << 2;
        const float* g = conv_w + (size_t)(i * CCH + cb * 64 + cl) * (2 * CCH)
                       + kb * 64 + kq;
        const float4 w1 = *(const float4*)g;
        const float4 w2 = *(const float4*)(g + CCH);
        *(float4*)(Ta + cl * 68 + kq) =
            make_float4(w1.x + w2.x, w1.y + w2.y, w1.z + w2.z, w1.w + w2.w);
        *(float4*)(Tw + cl * 68 + kq) = w2;
    }
    __syncthreads();

    // phase 2: coalesced write along c
#pragma unroll
    for (int p = 0; p < 4; ++p) {
        const int kl = p * 16 + (u >> 4);
        const int cq = (u & 15) << 2;
        float4 va, vw;
        va.x = Ta[(cq + 0) * 68 + kl];  vw.x = Tw[(cq + 0) * 68 + kl];
        va.y = Ta[(cq + 1) * 68 + kl];  vw.y = Tw[(cq + 1) * 68 + kl];
        va.z = Ta[(cq + 2) * 68 + kl];  vw.z = Tw[(cq + 2) * 68 + kl];
        va.w = Ta[(cq + 3) * 68 + kl];  vw.w = Tw[(cq + 3) * 68 + kl];
        float* o = ws + (size_t)(i * CCH + kb * 64 + kl) * CCH + cb * 64 + cq;
        *(float4*)o = va;
        *(float4*)(o + W2T_OFF) = vw;
    }
}

// ---------------- main ----------------
__global__ __launch_bounds__(384, 3)
void fub_main(const float* __restrict__ x, const float* __restrict__ wmat,
              const float* __restrict__ ws, const float* __restrict__ conv_b,
              float* __restrict__ out)
{
    __shared__ __align__(16) float smem[SMEM_FLOATS];
    float* Es = smem;                  // [6][16][SPAD] overlay (epilogue only)

    const int tid  = threadIdx.x;
    const int wv   = tid >> 6;        // 0..5 : stream id
    const int lane = tid & 63;

    // XCD-chunked bijective swizzle (1280 % 8 == 0)
    const int wg  = blockIdx.x;
    int L = (wg & 7) * 160 + (wg >> 3);
    const int i   = L % 5;  L /= 5;
    const int ct  = L & 3;  L >>= 2;
    const int b   = L & 3;  L >>= 2;
    const int hwt = L;                 // 0..15

    const int c0  = ct * CT;
    const int hw0 = hwt * WT;

    // ---- staging source (per-lane, column-swizzled) ----
    const int q    = lane & 15;
    const int invc = ((q & 7) << 1) | (q >> 3);   // cell stored at position q
    const int kr   = lane >> 4;                    // row within 4-row call

    const int jst = (wv < NN) ? wv : 0;            // wave w<5 stages Xs[w]
    const float* xsrc = x + ((size_t)(jst * BB + b) * CCH + kr) * HWD
                          + hw0 + invc * 4;
    const float* asrc  = ws + ((size_t)(i * CCH) + kr) * CCH + c0 + invc * 4;
    const float* w2src = asrc + W2T_OFF;

    // ---- compute-side bases (swizzled read: a0/x0 at g*4, a1/x1 at 32+g*4) ----
    const int jx    = (wv < NN) ? wv : i;
    const int msoff = (wv == 5) ? W2SO : ASO;
    const int aoff  = msoff + ((lane >> 3) << 2);
    const int xoff  = jx * 512 + ((lane & 7) << 2);

    float acc[8][8];
#pragma unroll
    for (int r = 0; r < 8; ++r)
#pragma unroll
        for (int c = 0; c < 8; ++c) acc[r][c] = 0.0f;

#define STAGE(K0, BO) do {                                                  \
        if (wv < NN) {                                                      \
            GL16(xsrc + (size_t)(K0) * HWD,           smem + (BO) + wv * 512);       \
            GL16(xsrc + (size_t)(K0) * HWD + 4 * HWD, smem + (BO) + wv * 512 + 256); \
        } else {                                                            \
            GL16(asrc  + (K0) * CCH,           smem + (BO) + ASO);          \
            GL16(asrc  + (K0) * CCH + 4 * CCH, smem + (BO) + ASO + 256);    \
            GL16(w2src + (K0) * CCH,           smem + (BO) + W2SO);         \
            GL16(w2src + (K0) * CCH + 4 * CCH, smem + (BO) + W2SO + 256);   \
        }                                                                   \
    } while (0)

#define COMPUTE(BO) do {                                                    \
        _Pragma("unroll")                                                   \
        for (int kk = 0; kk < KC; ++kk) {                                   \
            const float4 a0 = *(const float4*)(smem + (BO) + aoff + kk * 64);      \
            const float4 a1 = *(const float4*)(smem + (BO) + aoff + kk * 64 + 32); \
            const float4 x0 = *(const float4*)(smem + (BO) + xoff + kk * 64);      \
            const float4 x1 = *(const float4*)(smem + (BO) + xoff + kk * 64 + 32); \
            const float ar[8] = {a0.x,a0.y,a0.z,a0.w,a1.x,a1.y,a1.z,a1.w};  \
            const float xc[8] = {x0.x,x0.y,x0.z,x0.w,x1.x,x1.y,x1.z,x1.w};  \
            _Pragma("unroll")                                               \
            for (int r = 0; r < 8; ++r)                                     \
                _Pragma("unroll")                                           \
                for (int c = 0; c < 8; ++c)                                 \
                    acc[r][c] = fmaf(ar[r], xc[c], acc[r][c]);              \
        }                                                                   \
    } while (0)

    // prologue: chunk 0 -> buf0
    STAGE(0, 0);
    __syncthreads();

    // 32 chunks, 2-phase unrolled (static buffer offsets), 1 barrier/chunk.
    // STAGE(t+1) issued BEFORE compute(t): DMA latency hides under ~1024cy
    // of FMA; __syncthreads' vmcnt(0)+lgkmcnt(0) drain completes the handoff.
#pragma unroll 1
    for (int t = 0; t < 32; t += 2) {
        STAGE((t + 1) * KC, BUFSZ);
        COMPUTE(0);
        __syncthreads();
        if (t < 30) STAGE((t + 2) * KC, 0);
        COMPUTE(BUFSZ);
        __syncthreads();
    }

    // ---- epilogue: 4 passes over 16-row bands; exchange streams via LDS ----
    const int lr = (lane >> 3) << 3;
    const int lc = (lane & 7)  << 3;
    const int rhme  = lr >> 4;
    const int rbase = lr & 15;

    float wrow[NN];
#pragma unroll
    for (int j = 0; j < NN; ++j) wrow[j] = wmat[i * NN + j];

#pragma unroll
    for (int rh = 0; rh < 4; ++rh) {
        if (rhme == rh) {
            float* Eb = Es + wv * (16 * SPAD) + lc;
#pragma unroll
            for (int r = 0; r < 8; ++r) {
                *(float4*)(Eb + (rbase + r) * SPAD) =
                    make_float4(acc[r][0], acc[r][1], acc[r][2], acc[r][3]);
                *(float4*)(Eb + (rbase + r) * SPAD + 4) =
                    make_float4(acc[r][4], acc[r][5], acc[r][6], acc[r][7]);
            }
        }
        __syncthreads();

        if (tid < 256) {
            const int row  = tid >> 4;           // 0..15
            const int colq = (tid & 15) << 2;    // 0..60
            const int c    = c0 + rh * 16 + row;
            const float bias = conv_b[i * CCH + c];

            const float4 T = *(const float4*)(Es + 5 * (16 * SPAD) + row * SPAD + colq);
            const float Tv[4] = {T.x, T.y, T.z, T.w};

            float num[4] = {0.f, 0.f, 0.f, 0.f};
            float sq [4] = {0.f, 0.f, 0.f, 0.f};
#pragma unroll
            for (int j = 0; j < NN; ++j) {
                const float4 s  = *(const float4*)(Es + j * (16 * SPAD) + row * SPAD + colq);
                const float4 xj = *(const float4*)(
                    x + (size_t)((j * BB + b) * CCH + c) * HWD + hw0 + colq);
                const float sv[4] = {s.x, s.y, s.z, s.w};
                const float xv[4] = {xj.x, xj.y, xj.z, xj.w};
#pragma unroll
                for (int cc = 0; cc < 4; ++cc) {
                    const float target = sv[cc] + Tv[cc] + bias;
                    const float dist   = xv[cc] - target;
                    const float z      = dist * wrow[j];
                    float e = 1.0f / (1.0f + expf(-z));
                    e = (e > THRESH_V) ? e : 0.0f;
                    sq[cc]  = fmaf(e, e, sq[cc]);
                    num[cc] = fmaf(e, xv[cc], num[cc]);
                }
            }
            float4 res;
            res.x = num[0] / fmaxf(sqrtf(sq[0]), EPS_V);
            res.y = num[1] / fmaxf(sqrtf(sq[1]), EPS_V);
            res.z = num[2] / fmaxf(sqrtf(sq[2]), EPS_V);
            res.w = num[3] / fmaxf(sqrtf(sq[3]), EPS_V);
            *(float4*)(out + (size_t)((i * BB + b) * CCH + c) * HWD + hw0 + colq) = res;
        }
        __syncthreads();
    }
}

extern "C" void kernel_launch(void* const* d_in, const int* in_sizes, int n_in,
                              void* d_out, int out_size, void* d_ws, size_t ws_size,
                              hipStream_t stream) {
    const float* x      = (const float*)d_in[0];
    const float* w      = (const float*)d_in[1];
    const float* conv_w = (const float*)d_in[2];
    const float* conv_b = (const float*)d_in[3];
    float* out = (float*)d_out;
    float* ws  = (float*)d_ws;   // needs 2*5*256*256*4 B = 2.62 MB

    // prep: 5 i x 4 kb x 4 cb tiles, LDS transpose, coalesced both sides
    fub_prep<<<dim3(80), dim3(256), 0, stream>>>(conv_w, ws);

    // grid: hwt(16) * b(4) * ct(4) * i(5) = 1280 blocks of 384 threads
    fub_main<<<dim3(1280), dim3(384), 0, stream>>>(x, w, ws, conv_b, out);
}